// Round 1
// baseline (442.725 us; speedup 1.0000x reference)
//
#include <hip/hip_runtime.h>
#include <math.h>

// Problem constants (from reference): B=4, S=8192, H=2048, K=4, fp32.
#define CB 4
#define CS 8192
#define CH 2048
#define CH4 (CH / 4)      // 512 float4 groups per row
#define TT 64             // timesteps per thread (halo overhead 3/64 ~ 4.7%)

__device__ __forceinline__ float silu(float v) {
    return v / (1.0f + __expf(-v));
}

__global__ __launch_bounds__(256) void dwconv_silu_kernel(
        const float* __restrict__ x,
        const float* __restrict__ w,
        float* __restrict__ y) {
    const int tid = blockIdx.x * 256 + threadIdx.x;
    const int h4 = tid & (CH4 - 1);          // consecutive lanes -> consecutive float4 in H: coalesced
    const int strip = tid >> 9;              // tid / 512
    const int b = strip >> 7;                // / (S/TT = 128)
    const int t0 = (strip & 127) * TT;

    const float4* __restrict__ xb = reinterpret_cast<const float4*>(x) + (size_t)b * CS * CH4 + h4;
    float4* __restrict__ yb = reinterpret_cast<float4*>(y) + (size_t)b * CS * CH4 + h4;

    // Weight rows for channels h = 4*h4 .. 4*h4+3. wr{c}.x..w = w[h, 0..3]
    const float4* __restrict__ wv = reinterpret_cast<const float4*>(w) + (size_t)h4 * 4;
    const float4 wr0 = wv[0];
    const float4 wr1 = wv[1];
    const float4 wr2 = wv[2];
    const float4 wr3 = wv[3];

    const float4 z = make_float4(0.f, 0.f, 0.f, 0.f);
    // Sliding window: x[t-3], x[t-2], x[t-1] (zero-padded at sequence start).
    float4 xm3 = (t0 >= 3) ? xb[(size_t)(t0 - 3) * CH4] : z;
    float4 xm2 = (t0 >= 2) ? xb[(size_t)(t0 - 2) * CH4] : z;
    float4 xm1 = (t0 >= 1) ? xb[(size_t)(t0 - 1) * CH4] : z;

    #pragma unroll 8
    for (int t = t0; t < t0 + TT; ++t) {
        const float4 cur = xb[(size_t)t * CH4];

        float4 o;
        o.x = wr0.x * xm3.x + wr0.y * xm2.x + wr0.z * xm1.x + wr0.w * cur.x;
        o.y = wr1.x * xm3.y + wr1.y * xm2.y + wr1.z * xm1.y + wr1.w * cur.y;
        o.z = wr2.x * xm3.z + wr2.y * xm2.z + wr2.z * xm1.z + wr2.w * cur.z;
        o.w = wr3.x * xm3.w + wr3.y * xm2.w + wr3.z * xm1.w + wr3.w * cur.w;

        o.x = silu(o.x);
        o.y = silu(o.y);
        o.z = silu(o.z);
        o.w = silu(o.w);

        yb[(size_t)t * CH4] = o;

        xm3 = xm2;
        xm2 = xm1;
        xm1 = cur;
    }
}

extern "C" void kernel_launch(void* const* d_in, const int* in_sizes, int n_in,
                              void* d_out, int out_size, void* d_ws, size_t ws_size,
                              hipStream_t stream) {
    const float* x = (const float*)d_in[0];   // (B, S, H) fp32
    const float* w = (const float*)d_in[1];   // (H, K) fp32
    float* y = (float*)d_out;                 // (B, S, H) fp32

    const int total_threads = CB * (CS / TT) * CH4;  // 4 * 128 * 512 = 262144
    dwconv_silu_kernel<<<total_threads / 256, 256, 0, stream>>>(x, w, y);
}